// Round 14
// baseline (149.691 us; speedup 1.0000x reference)
//
#include <hip/hip_runtime.h>
#include <cstdint>

using u16 = unsigned short;
using u32 = uint32_t;

typedef __attribute__((ext_vector_type(8))) short bf16x8;   // 8 bf16 = 4 VGPRs
typedef __attribute__((ext_vector_type(4))) float f32x4;    // MFMA accumulator

__device__ __forceinline__ float bf2f(u16 v) { return __uint_as_float(((u32)v) << 16); }
__device__ __forceinline__ u16 f2bf(float f) {
    u32 u = __float_as_uint(f);
    u += 0x7fffu + ((u >> 16) & 1u);   // RNE
    return (u16)(u >> 16);
}
// Native bf16 conversion (RNE); compiler may fuse pairs into v_cvt_pk_bf16_f32.
__device__ __forceinline__ u16 bf16u(float f) {
#if defined(__BF16_MANT_DIG__)
    __bf16 h = (__bf16)f;
    return __builtin_bit_cast(u16, h);
#else
    return f2bf(f);
#endif
}
// Raw hardware exp2 (v_exp_f32); flush-to-zero below 2^-126 is exactly right
// for softmax. Overflow handled by the +80 cap at call sites.
__device__ __forceinline__ float fexp2(float x) {
#if __has_builtin(__builtin_amdgcn_exp2f)
    return __builtin_amdgcn_exp2f(x);
#else
    float r; asm("v_exp_f32 %0, %1" : "=v"(r) : "v"(x)); return r;
#endif
}

// Per-block dtype sniff (verified logic; deterministic across blocks).
__device__ __forceinline__ int block_flag(const u16* __restrict__ x) {
    __shared__ int cnt;
    if (threadIdx.x == 0) cnt = 0;
    __syncthreads();
    int c = 0;
    #pragma unroll
    for (int k = 0; k < 16; k++) {
        u16 v = x[threadIdx.x * 16 + k];
        int e = (v >> 7) & 0xFF;
        c += (e >= 110 && e <= 140) ? 1 : 0;
    }
    atomicAdd(&cnt, c);
    __syncthreads();
    return (cnt > 3300) ? 1 : 0;
}

// ---- workspace float offsets ----
#define FLAG_OFF 0
#define ZERO_OFF 8         // 16 floats of guaranteed zeros
#define WSH_OFF  2097168   // conv weight bf16 fragments: u16[442368] = 221184 f
#define AWF_OFF  2588688   // 4096
#define CBF_OFF  2592784   // 192
#define QBF_OFF  2592976   // 192
#define ABF_OFF  2593168   // 64
#define KRW_OFF  2593232   // 504
#define KRH_OFF  2593736   // 504
#define KB_OFF   2594240   // kbuf bf16: u16[524288] (uses half the slot)
#define QB_OFF   3118528   // qbuf f32: 524288
#define VB_OFF   3642816   // vbuf bf16: u16[524288]
#define AT_OFF   4167104   // 524288
#define XBF_OFF  4691392   // x as bf16: u16[2097152] = 1048576 f (4 MB)
#define WSHQ_OFF 9409984   // qkv weight bf16 fragments: u16[49152] = 24576 f

// ---------------------------------------------------------------------------
// prepx: merged detect + prep + xcvt (R12-verified, unchanged).
//   blocks 0..215   : conv weight shuffle
//   blocks 216..239 : qkv weight shuffle
//   blocks 240..261 : small-tensor fp32 normalize (+zbuf)
//   blocks 262..1285: x -> bf16 conversion (flat xbf)
// ---------------------------------------------------------------------------
__global__ __launch_bounds__(256) void prepx_kernel(
    const u16* __restrict__ x0,
    const void* __restrict__ cw, const void* __restrict__ qw,
    const void* __restrict__ cb, const void* __restrict__ qb,
    const void* __restrict__ aw, const void* __restrict__ ab,
    const void* __restrict__ kw_, const void* __restrict__ kh_,
    u16* __restrict__ wshC, u16* __restrict__ wshQ,
    float* __restrict__ cbf, float* __restrict__ qbf, float* __restrict__ awf,
    float* __restrict__ abf, float* __restrict__ krw, float* __restrict__ krh,
    float* __restrict__ zbuf, int* __restrict__ flagws, u16* __restrict__ xbf)
{
    const int blk = blockIdx.x;
    const int fl = block_flag(x0);
    if (blk == 0 && threadIdx.x == 0) *flagws = fl;

    if (blk < 240) {                         // weight shuffles into B-fragment order
        const void* w; u16* o; int g;
        if (blk < 216) { w = cw; o = wshC; g = blk * 256 + threadIdx.x; }
        else           { w = qw; o = wshQ; g = (blk - 216) * 256 + threadIdx.x; }
        const int kk = g / 768, rem = g % 768;
        const int tile = rem >> 6, lane = rem & 63;
        const int n = tile * 16 + (lane & 15);
        u16 tmp[8];
        #pragma unroll
        for (int j = 0; j < 8; j++) {
            const size_t k = (size_t)(kk * 32 + ((lane >> 4) << 3) + j);
            tmp[j] = fl ? ((const u16*)w)[k * 192 + n]
                        : f2bf(((const float*)w)[k * 192 + n]);
        }
        *(uint4*)(o + (size_t)g * 8) = *(const uint4*)tmp;
    } else if (blk < 262) {                  // small-tensor fp32 normalize
        const int gid = (blk - 240) * 256 + threadIdx.x;
        const void* src; float* dst; int e;
        if      (gid <  192) { src = cb;  dst = cbf; e = gid; }
        else if (gid <  384) { src = qb;  dst = qbf; e = gid - 192; }
        else if (gid < 4480) { src = aw;  dst = awf; e = gid - 384; }
        else if (gid < 4544) { src = ab;  dst = abf; e = gid - 4480; }
        else if (gid < 5048) { src = kw_; dst = krw; e = gid - 4544; }
        else if (gid < 5552) { src = kh_; dst = krh; e = gid - 5048; }
        else if (gid < 5568) { zbuf[gid - 5552] = 0.f; return; }
        else return;
        dst[e] = fl ? bf2f(((const u16*)src)[e]) : ((const float*)src)[e];
    } else {                                 // xcvt: x -> bf16 (verified)
        const int g = (blk - 262) * 256 + threadIdx.x;     // 0..262143
        if (fl) {
            *(uint4*)(xbf + (size_t)g * 8) = *(const uint4*)(x0 + (size_t)g * 8);
        } else {
            const float* src = (const float*)x0 + (size_t)g * 8;
            float4 a = *(const float4*)src, b = *(const float4*)(src + 4);
            uint4 o;
            o.x = (u32)f2bf(a.x) | ((u32)f2bf(a.y) << 16);
            o.y = (u32)f2bf(a.z) | ((u32)f2bf(a.w) << 16);
            o.z = (u32)f2bf(b.x) | ((u32)f2bf(b.y) << 16);
            o.w = (u32)f2bf(b.z) | ((u32)f2bf(b.w) << 16);
            *(uint4*)(xbf + (size_t)g * 8) = o;
        }
    }
}

// ---------------------------------------------------------------------------
// qc: merged conv (blocks 0..255) + qkv (256..767). Conv change vs R12:
// ONE block per row computes ALL 192 channels; each wave owns 3 channel-tiles
// x BOTH M-tiles (acc[2][3], tg0 = wave*3). Each weight B-fragment now feeds
// 2 MFMAs instead of 1 -> conv weight L2 traffic halves (442 -> 221 MB), and
// each row is staged once instead of twice. Same kk order per output ->
// bit-identical results. Rotating 2-slot staging (R12-verified) unchanged.
// ---------------------------------------------------------------------------
__global__ __launch_bounds__(256) void qc_kernel(
    const u16* __restrict__ xbf, const u16* __restrict__ wshC, const u16* __restrict__ wshQ,
    const float* __restrict__ cbf, const float* __restrict__ qbf_,
    const int* __restrict__ flagws,
    u16* __restrict__ kb16, float* __restrict__ qbuf, u16* __restrict__ vb16,
    void* __restrict__ out)
{
    __shared__ u16 xs[2 * 34 * 264];                        // 35904 B
    const int blk = blockIdx.x;
    const int t = threadIdx.x;
    const int lane = t & 63, wave = t >> 6;
    const int l15 = lane & 15, quad = lane >> 4;

    if (blk < 256) {
        // ===== conv role: all 192 channels, both M-tiles per wave =====
        const int row = blk;
        const int b = row >> 5, h = row & 31;
        const int fl = *flagws;
        const int tg0 = wave * 3;            // 4 waves x 3 tiles = 12 = 192 ch
        f32x4 acc[2][3] = {{{0,0,0,0},{0,0,0,0},{0,0,0,0}},
                           {{0,0,0,0},{0,0,0,0},{0,0,0,0}}};

        #define STAGE_ROW(R, S)                                                  \
          do {                                                                   \
            const int hh = h + (R) - 1;                                          \
            if (t < 64) {                                                        \
                const int e = (t >> 5) ? 33 : 0, cq = t & 31;                    \
                *(uint4*)(xs + ((S) * 34 + e) * 264 + cq * 8) = make_uint4(0,0,0,0); \
            }                                                                    \
            const bool ok = (hh >= 0) && (hh < 32);                              \
            const u16* src = xbf + ((size_t)((b * 32 + (ok ? hh : 0)) * 32)) * 256; \
            _Pragma("unroll")                                                    \
            for (int i = 0; i < 4; ++i) {                                        \
                const int idx = t + i * 256;                                     \
                const int px = idx >> 5, cq = idx & 31;                          \
                uint4 v = ok ? *(const uint4*)(src + px * 256 + cq * 8)          \
                             : make_uint4(0, 0, 0, 0);                           \
                *(uint4*)(xs + ((S) * 34 + 1 + px) * 264 + cq * 8) = v;          \
            }                                                                    \
          } while (0)

        // one kh band from slot S; each B-fragment feeds both M-tiles.
        #define CONV_KH(KH, S)                                                   \
          do {                                                                   \
            _Pragma("unroll")                                                    \
            for (int kw = 0; kw < 3; ++kw) {                                     \
              const u16* ap0 = xs + ((S) * 34 + kw + l15) * 264 + quad * 8;      \
              const u16* ap1 = ap0 + 16 * 264;                                   \
              _Pragma("unroll")                                                  \
              for (int ck = 0; ck < 8; ++ck) {                                   \
                const int kk = ((KH) * 3 + kw) * 8 + ck;                         \
                const bf16x8 av0 = *(const bf16x8*)(ap0 + ck * 32);              \
                const bf16x8 av1 = *(const bf16x8*)(ap1 + ck * 32);              \
                const u16* wp = wshC + ((size_t)(kk * 12 + tg0) * 64 + lane) * 8;\
                const bf16x8 b0 = *(const bf16x8*)(wp);                          \
                const bf16x8 b1 = *(const bf16x8*)(wp + 512);                    \
                const bf16x8 b2 = *(const bf16x8*)(wp + 1024);                   \
                acc[0][0] = __builtin_amdgcn_mfma_f32_16x16x32_bf16(av0, b0, acc[0][0], 0, 0, 0); \
                acc[0][1] = __builtin_amdgcn_mfma_f32_16x16x32_bf16(av0, b1, acc[0][1], 0, 0, 0); \
                acc[0][2] = __builtin_amdgcn_mfma_f32_16x16x32_bf16(av0, b2, acc[0][2], 0, 0, 0); \
                acc[1][0] = __builtin_amdgcn_mfma_f32_16x16x32_bf16(av1, b0, acc[1][0], 0, 0, 0); \
                acc[1][1] = __builtin_amdgcn_mfma_f32_16x16x32_bf16(av1, b1, acc[1][1], 0, 0, 0); \
                acc[1][2] = __builtin_amdgcn_mfma_f32_16x16x32_bf16(av1, b2, acc[1][2], 0, 0, 0); \
              }                                                                  \
            }                                                                    \
          } while (0)

        STAGE_ROW(0, 0);
        STAGE_ROW(1, 1);
        __syncthreads();
        CONV_KH(0, 0);
        __syncthreads();                     // all waves done reading slot 0
        STAGE_ROW(2, 0);                     // overlaps with kh=1 compute below
        CONV_KH(1, 1);
        __syncthreads();                     // slot-0 writes visible
        CONV_KH(2, 0);

        #pragma unroll
        for (int mt = 0; mt < 2; ++mt) {
            const int px0 = mt * 16 + quad * 4;
            #pragma unroll
            for (int ti = 0; ti < 3; ++ti) {
                const int co = (tg0 + ti) * 16 + l15;
                const float bias = cbf[co];
                #pragma unroll
                for (int r = 0; r < 4; ++r) {
                    const size_t oidx = ((size_t)row * 32 + px0 + r) * 256 + co;
                    const float v = acc[mt][ti][r] + bias;
                    if (fl) ((u16*)out)[oidx] = f2bf(v);
                    else    ((float*)out)[oidx] = v;
                }
            }
        }
        #undef STAGE_ROW
        #undef CONV_KH
    } else {
        // ================= qkv role (R12-verified body) =================
        const int idx2 = blk - 256;
        const int coh = idx2 & 1, row = idx2 >> 1;
        const int b = row >> 5, h = row & 31;
        const int Mtile = wave & 1;

        {
            const u16* src = xbf + (size_t)row * 8192;
            #pragma unroll
            for (int i = 0; i < 4; ++i) {
                const int idx = t + i * 256;
                const int px = idx >> 5, cq = idx & 31;
                *(uint4*)(xs + px * 264 + cq * 8) = *(const uint4*)(src + px * 256 + cq * 8);
            }
        }
        __syncthreads();

        const int tg0 = coh * 6 + (wave >> 1) * 3;
        f32x4 acc[3] = {{0,0,0,0},{0,0,0,0},{0,0,0,0}};

        const u16* ap = xs + (Mtile * 16 + l15) * 264 + quad * 8;
        #pragma unroll
        for (int kk = 0; kk < 8; ++kk) {
            const bf16x8 av = *(const bf16x8*)(ap + kk * 32);
            const u16* wp = wshQ + ((size_t)(kk * 12 + tg0) * 64 + lane) * 8;
            const bf16x8 b0 = *(const bf16x8*)(wp);
            const bf16x8 b1 = *(const bf16x8*)(wp + 512);
            const bf16x8 b2 = *(const bf16x8*)(wp + 1024);
            acc[0] = __builtin_amdgcn_mfma_f32_16x16x32_bf16(av, b0, acc[0], 0, 0, 0);
            acc[1] = __builtin_amdgcn_mfma_f32_16x16x32_bf16(av, b1, acc[1], 0, 0, 0);
            acc[2] = __builtin_amdgcn_mfma_f32_16x16x32_bf16(av, b2, acc[2], 0, 0, 0);
        }

        // D layout (verified): col = lane&15, row = quad*4 + reg
        const int px0 = Mtile * 16 + quad * 4;
        #pragma unroll
        for (int ti = 0; ti < 3; ++ti) {
            const int tg = tg0 + ti;
            const int o = tg * 16 + l15;
            const int third = tg >> 2;                      // 0=k,1=q,2=v (wave-uniform)
            const int within = o - third * 64;
            const int n = within >> 3, d = within & 7;
            const float bias = qbf_[o];
            #pragma unroll
            for (int r = 0; r < 4; ++r) {
                const int i = h * 32 + px0 + r;
                const size_t off = ((size_t)(b * 8 + n) * 1024 + i) * 8 + d;
                const float val = acc[ti][r] + bias;
                if (third == 0)      kb16[off] = f2bf(val);
                else if (third == 1) qbuf[off] = val * 0.51006973050f;  // 8^-.5 * log2e
                else                 vb16[off] = f2bf(val);
            }
        }
    }
}

// ---------------------------------------------------------------------------
// MFMA flash attention v10 — GREEN (R9-R12 verified). Unchanged.
// ---------------------------------------------------------------------------
#define ATTN_STEPA(C, KA, KB, OACC)                                            \
  do {                                                                         \
    const int c_ = (C);                                                        \
    const float rhv = sRH[c_ * 36 + pair * 16 + l15];                          \
    f32x4 acc0, acc1;                                                          \
    acc0[0] = rhv + rw0[0]; acc0[1] = rhv + rw0[1];                            \
    acc0[2] = rhv + rw0[2]; acc0[3] = rhv + rw0[3];                            \
    acc1[0] = rhv + rw1[0]; acc1[1] = rhv + rw1[1];                            \
    acc1[2] = rhv + rw1[2]; acc1[3] = rhv + rw1[3];                            \
    acc0 = __builtin_amdgcn_mfma_f32_16x16x32_bf16(KA, Aq.v, acc0, 0, 0, 0);   \
    acc1 = __builtin_amdgcn_mfma_f32_16x16x32_bf16(KB, Aq.v, acc1, 0, 0, 0);   \
    if (c_ + 4 < 32) {            /* prefetch 4 chunks ahead (ping-pong) */    \
      KA = *(const bf16x8*)(kp0 + (c_ + 4) * 256);                             \
      KB = *(const bf16x8*)(kp1 + (c_ + 4) * 256);                             \
    }                                                                          \
    union { u16 a[8]; bf16x8 v; } pf;                                          \
    pf.a[0] = bf16u(fexp2(fminf(acc0[0], 80.0f)));                             \
    pf.a[1] = bf16u(fexp2(fminf(acc0[1], 80.0f)));                             \
    pf.a[2] = bf16u(fexp2(fminf(acc0[2], 80.0f)));                             \
    pf.a[3] = bf16u(fexp2(fminf(acc0[3], 80.0f)));                             \
    pf.a[4] = bf16u(fexp2(fminf(acc1[0], 80.0f)));                             \
    pf.a[5] = bf16u(fexp2(fminf(acc1[1], 80.0f)));                             \
    pf.a[6] = bf16u(fexp2(fminf(acc1[2], 80.0f)));                             \
    pf.a[7] = bf16u(fexp2(fminf(acc1[3], 80.0f)));                             \
    bf16x8 Av;                                                                 \
    if (l15 < 8) Av = *(const bf16x8*)(sVT + l15 * 1032 + c_ * 32 + quad * 8); \
    else         Av = ONE.v;                                                   \
    OACC = __builtin_amdgcn_mfma_f32_16x16x32_bf16(Av, pf.v, OACC, 0, 0, 0);   \
  } while (0)

__global__ __launch_bounds__(256) void attn_mfma_kernel(
    const u16* __restrict__ kb16, const float* __restrict__ qbuf, const u16* __restrict__ vb16,
    const float* __restrict__ krw, const float* __restrict__ krh,
    float* __restrict__ attnbuf)
{
    const int qb = blockIdx.x;           // 0..31 (32 q-rows each)
    const int bn = blockIdx.y;           // 0..63
    const int b = bn >> 3, hn = bn & 7;
    const int t = threadIdx.x;
    const int i0 = qb * 32;

    __shared__ __align__(16) u16   sVT[8 * 1032];   // [d][key] bf16 (pad)  16512 B
    __shared__ __align__(16) u16   sRW[32 * 40];    // [ilocal][wk] bf16     2560 B
    __shared__ __align__(16) float sRH[32 * 36];    // [hk][ilocal] f32      4608 B
    __shared__ __align__(16) float sRed[2 * 64 * 4];// pair partials         2048 B

    // ---- stage V^T from bf16 vbuf (no conversion) — verified ----
    const u16* vg = vb16 + (size_t)bn * 8192;
    #pragma unroll
    for (int k4 = 0; k4 < 4; k4++) {
        const int key = t + k4 * 256;                 // 0..1023
        uint4 vv = *(const uint4*)(vg + key * 8);
        sVT[0 * 1032 + key] = (u16)(vv.x);  sVT[1 * 1032 + key] = (u16)(vv.x >> 16);
        sVT[2 * 1032 + key] = (u16)(vv.y);  sVT[3 * 1032 + key] = (u16)(vv.y >> 16);
        sVT[4 * 1032 + key] = (u16)(vv.z);  sVT[5 * 1032 + key] = (u16)(vv.z >> 16);
        sVT[6 * 1032 + key] = (u16)(vv.w);  sVT[7 * 1032 + key] = (u16)(vv.w >> 16);
    }
    // ---- rel tables (verified math; 32 q-rows) ----
    #pragma unroll
    for (int k8 = 0; k8 < 4; k8++) {
        const int idx = t + k8 * 256;                 // 0..1023
        const int il = idx >> 5, w = idx & 31;        // il 0..31
        const int i = i0 + il;
        const float* q = qbuf + ((size_t)bn * 1024 + i) * 8;
        float4 qa = *(const float4*)q, qc = *(const float4*)(q + 4);
        const float* rp = krw + (size_t)(w - (i & 31) + 31) * 8;
        float4 ra = *(const float4*)rp, rc = *(const float4*)(rp + 4);
        sRW[il * 40 + w] = f2bf(qa.x*ra.x + qa.y*ra.y + qa.z*ra.z + qa.w*ra.w
                              + qc.x*rc.x + qc.y*rc.y + qc.z*rc.z + qc.w*rc.w);
        const float* hp = krh + (size_t)(w - (i >> 5) + 31) * 8;
        float4 ha = *(const float4*)hp, hc = *(const float4*)(hp + 4);
        sRH[w * 36 + il] = qa.x*ha.x + qa.y*ha.y + qa.z*ha.z + qa.w*ha.w
                         + qc.x*hc.x + qc.y*hc.y + qc.z*hc.z + qc.w*hc.w;
    }
    __syncthreads();

    const int lane = t & 63, wave = t >> 6;
    const int pair = wave >> 1, sub = wave & 1;
    const int l15 = lane & 15, quad = lane >> 4;

    union Frag { u16 a[8]; bf16x8 v; };
    Frag Aq;                                   // Q fragment (B operand)
    {
        const float* q = qbuf + ((size_t)bn * 1024 + i0 + pair * 16 + l15) * 8;
        float4 qa = *(const float4*)q, qc = *(const float4*)(q + 4);
        Aq.a[0] = f2bf(qa.x); Aq.a[1] = f2bf(qa.y); Aq.a[2] = f2bf(qa.z); Aq.a[3] = f2bf(qa.w);
        Aq.a[4] = f2bf(qc.x); Aq.a[5] = f2bf(qc.y); Aq.a[6] = f2bf(qc.z); Aq.a[7] = f2bf(qc.w);
        if (quad != 0) {
            #pragma unroll
            for (int j = 0; j < 8; j++) Aq.a[j] = 0;
        }
    }
    const bf16x8 Arw = *(const bf16x8*)(sRW + (pair * 16 + l15) * 40 + quad * 8);

    // Selector fragments (verified): S0 -> k=pi0(l15), S1 -> k=pi1(l15).
    Frag S0, S1, ONE;
    #pragma unroll
    for (int j = 0; j < 8; j++) { S0.a[j] = 0; S1.a[j] = 0; ONE.a[j] = 0x3F80; }
    if (quad == (l15 >> 2)) {
        S0.a[l15 & 3]       = 0x3F80;
        S1.a[4 + (l15 & 3)] = 0x3F80;
    }

    // Hoisted rel-W results (chunk-invariant).
    f32x4 zero4 = {0.f, 0.f, 0.f, 0.f};
    const f32x4 rw0 = __builtin_amdgcn_mfma_f32_16x16x32_bf16(S0.v, Arw, zero4, 0, 0, 0);
    const f32x4 rw1 = __builtin_amdgcn_mfma_f32_16x16x32_bf16(S1.v, Arw, zero4, 0, 0, 0);

    // K row pointers — uniform across quads (verified).
    const u16* kg = kb16 + (size_t)bn * 8192;
    const int s = l15 >> 2, rr = l15 & 3;
    const u16* kp0 = kg + (size_t)(8 * s + rr) * 8;          // pi0 rows
    const u16* kp1 = kg + (size_t)(8 * s + 4 + rr) * 8;      // pi1 rows

    f32x4 oaccE = {0.f, 0.f, 0.f, 0.f};
    f32x4 oaccO = {0.f, 0.f, 0.f, 0.f};

    // This wave's chunks: sub, sub+2, ..., sub+30 (16 chunks).
    bf16x8 kAa = *(const bf16x8*)(kp0 + sub * 256);
    bf16x8 kBa = *(const bf16x8*)(kp1 + sub * 256);
    bf16x8 kAb = *(const bf16x8*)(kp0 + (sub + 2) * 256);
    bf16x8 kBb = *(const bf16x8*)(kp1 + (sub + 2) * 256);

    for (int c2 = sub; c2 < 32; c2 += 4) {
        ATTN_STEPA(c2,     kAa, kBa, oaccE);
        ATTN_STEPA(c2 + 2, kAb, kBb, oaccO);
    }

    f32x4 oacc;
    oacc[0] = oaccE[0] + oaccO[0];
    oacc[1] = oaccE[1] + oaccO[1];
    oacc[2] = oaccE[2] + oaccO[2];
    oacc[3] = oaccE[3] + oaccO[3];

    // Pair reduction: sub==1 writes partials; sub==0 adds.
    if (sub == 1) *(f32x4*)(sRed + (pair * 64 + lane) * 4) = oacc;
    __syncthreads();
    if (sub == 0) {
        const f32x4 part = *(const f32x4*)(sRed + (pair * 64 + lane) * 4);
        oacc[0] += part[0]; oacc[1] += part[1];
        oacc[2] += part[2]; oacc[3] += part[3];

        // D2[row][q=l15]: rows 0-7 = O^T[d][q] (quads 0,1), rows 8-15 = l[q].
        const float lr = __shfl(oacc[0], 32 + l15, 64);   // (l15, quad=2) row 8
        const float inv = 1.0f / fmaxf(lr, 1e-30f);
        if (quad < 2) {
            float4 o;
            o.x = oacc[0] * inv; o.y = oacc[1] * inv;
            o.z = oacc[2] * inv; o.w = oacc[3] * inv;
            *(float4*)(attnbuf + ((size_t)b * 1024 + i0 + pair * 16 + l15) * 64
                       + hn * 8 + quad * 4) = o;
        }
    }
}

// ---------------------------------------------------------------------------
// Output projection (verified body; flag read from ws).
// ---------------------------------------------------------------------------
__global__ __launch_bounds__(256) void proj_kernel(
    const float* __restrict__ attnbuf, const float* __restrict__ awf, const float* __restrict__ abf,
    const int* __restrict__ flagws, void* __restrict__ out)
{
    const int g = blockIdx.x * 256 + threadIdx.x;
    const int px = g >> 6, o = g & 63;
    const float* ar = attnbuf + (size_t)px * 64;
    float acc = abf[o];
    #pragma unroll 8
    for (int c = 0; c < 64; c++) acc += ar[c] * awf[c * 64 + o];
    if (*flagws) ((u16*)out)[(size_t)px * 256 + 192 + o] = f2bf(acc);
    else         ((float*)out)[(size_t)px * 256 + 192 + o] = acc;
}

// ---------------------------------------------------------------------------
extern "C" void kernel_launch(void* const* d_in, const int* in_sizes, int n_in,
                              void* d_out, int out_size, void* d_ws, size_t ws_size,
                              hipStream_t stream)
{
    float* ws = (float*)d_ws;
    int*   flag = (int*)(ws + FLAG_OFF);
    float* zbuf = ws + ZERO_OFF;
    u16*   wsh  = (u16*)(ws + WSH_OFF);
    float* awf  = ws + AWF_OFF;
    float* cbf  = ws + CBF_OFF;
    float* qbf  = ws + QBF_OFF;
    float* abf  = ws + ABF_OFF;
    float* krw  = ws + KRW_OFF;
    float* krh  = ws + KRH_OFF;
    u16*   kb16 = (u16*)(ws + KB_OFF);
    float* qbuf = ws + QB_OFF;
    u16*   vb16 = (u16*)(ws + VB_OFF);
    float* atb  = ws + AT_OFF;
    u16*   xbf  = (u16*)(ws + XBF_OFF);
    u16*   wshQ = (u16*)(ws + WSHQ_OFF);

    prepx_kernel<<<1286, 256, 0, stream>>>(
        (const u16*)d_in[0],
        d_in[1], d_in[3], d_in[2], d_in[4], d_in[5], d_in[6], d_in[7], d_in[8],
        wsh, wshQ, cbf, qbf, awf, abf, krw, krh, zbuf, flag, xbf);

    qc_kernel<<<768, 256, 0, stream>>>(
        xbf, wsh, wshQ, cbf, qbf, flag, kb16, qbuf, vb16, d_out);

    attn_mfma_kernel<<<dim3(32, 64), 256, 0, stream>>>(kb16, qbuf, vb16, krw, krh, atb);
    proj_kernel     <<<2048,         256, 0, stream>>>(atb, awf, abf, flag, d_out);
}

// Round 15
// 144.331 us; speedup vs baseline: 1.0371x; 1.0371x over previous
//
#include <hip/hip_runtime.h>
#include <cstdint>

using u16 = unsigned short;
using u32 = uint32_t;

typedef __attribute__((ext_vector_type(8))) short bf16x8;   // 8 bf16 = 4 VGPRs
typedef __attribute__((ext_vector_type(4))) float f32x4;    // MFMA accumulator

__device__ __forceinline__ float bf2f(u16 v) { return __uint_as_float(((u32)v) << 16); }
__device__ __forceinline__ u16 f2bf(float f) {
    u32 u = __float_as_uint(f);
    u += 0x7fffu + ((u >> 16) & 1u);   // RNE
    return (u16)(u >> 16);
}
// Native bf16 conversion (RNE); compiler may fuse pairs into v_cvt_pk_bf16_f32.
__device__ __forceinline__ u16 bf16u(float f) {
#if defined(__BF16_MANT_DIG__)
    __bf16 h = (__bf16)f;
    return __builtin_bit_cast(u16, h);
#else
    return f2bf(f);
#endif
}
// Raw hardware exp2 (v_exp_f32); flush-to-zero below 2^-126 is exactly right
// for softmax. Overflow handled by the +80 cap at call sites.
__device__ __forceinline__ float fexp2(float x) {
#if __has_builtin(__builtin_amdgcn_exp2f)
    return __builtin_amdgcn_exp2f(x);
#else
    float r; asm("v_exp_f32 %0, %1" : "=v"(r) : "v"(x)); return r;
#endif
}

// Per-block dtype sniff (verified logic; deterministic across blocks).
__device__ __forceinline__ int block_flag(const u16* __restrict__ x) {
    __shared__ int cnt;
    if (threadIdx.x == 0) cnt = 0;
    __syncthreads();
    int c = 0;
    #pragma unroll
    for (int k = 0; k < 16; k++) {
        u16 v = x[threadIdx.x * 16 + k];
        int e = (v >> 7) & 0xFF;
        c += (e >= 110 && e <= 140) ? 1 : 0;
    }
    atomicAdd(&cnt, c);
    __syncthreads();
    return (cnt > 3300) ? 1 : 0;
}

// ---- workspace float offsets ----
#define FLAG_OFF 0
#define ZERO_OFF 8         // 16 floats of guaranteed zeros
#define WSH_OFF  2097168   // conv weight bf16 fragments: u16[442368] = 221184 f
#define AWF_OFF  2588688   // 4096
#define CBF_OFF  2592784   // 192
#define QBF_OFF  2592976   // 192
#define ABF_OFF  2593168   // 64
#define KRW_OFF  2593232   // 504
#define KRH_OFF  2593736   // 504
#define KB_OFF   2594240   // kbuf bf16: u16[524288] (uses half the slot)
#define QB_OFF   3118528   // qbuf f32: 524288
#define VB_OFF   3642816   // vbuf bf16: u16[524288]
#define AT_OFF   4167104   // 524288
#define XBF_OFF  4691392   // x as bf16: u16[2097152] = 1048576 f (4 MB)
#define WSHQ_OFF 9409984   // qkv weight bf16 fragments: u16[49152] = 24576 f

// ---------------------------------------------------------------------------
// prepx: merged detect + prep + xcvt (R12-verified, unchanged).
//   blocks 0..215   : conv weight shuffle
//   blocks 216..239 : qkv weight shuffle
//   blocks 240..261 : small-tensor fp32 normalize (+zbuf)
//   blocks 262..1285: x -> bf16 conversion (flat xbf)
// ---------------------------------------------------------------------------
__global__ __launch_bounds__(256) void prepx_kernel(
    const u16* __restrict__ x0,
    const void* __restrict__ cw, const void* __restrict__ qw,
    const void* __restrict__ cb, const void* __restrict__ qb,
    const void* __restrict__ aw, const void* __restrict__ ab,
    const void* __restrict__ kw_, const void* __restrict__ kh_,
    u16* __restrict__ wshC, u16* __restrict__ wshQ,
    float* __restrict__ cbf, float* __restrict__ qbf, float* __restrict__ awf,
    float* __restrict__ abf, float* __restrict__ krw, float* __restrict__ krh,
    float* __restrict__ zbuf, int* __restrict__ flagws, u16* __restrict__ xbf)
{
    const int blk = blockIdx.x;
    const int fl = block_flag(x0);
    if (blk == 0 && threadIdx.x == 0) *flagws = fl;

    if (blk < 240) {                         // weight shuffles into B-fragment order
        const void* w; u16* o; int g;
        if (blk < 216) { w = cw; o = wshC; g = blk * 256 + threadIdx.x; }
        else           { w = qw; o = wshQ; g = (blk - 216) * 256 + threadIdx.x; }
        const int kk = g / 768, rem = g % 768;
        const int tile = rem >> 6, lane = rem & 63;
        const int n = tile * 16 + (lane & 15);
        u16 tmp[8];
        #pragma unroll
        for (int j = 0; j < 8; j++) {
            const size_t k = (size_t)(kk * 32 + ((lane >> 4) << 3) + j);
            tmp[j] = fl ? ((const u16*)w)[k * 192 + n]
                        : f2bf(((const float*)w)[k * 192 + n]);
        }
        *(uint4*)(o + (size_t)g * 8) = *(const uint4*)tmp;
    } else if (blk < 262) {                  // small-tensor fp32 normalize
        const int gid = (blk - 240) * 256 + threadIdx.x;
        const void* src; float* dst; int e;
        if      (gid <  192) { src = cb;  dst = cbf; e = gid; }
        else if (gid <  384) { src = qb;  dst = qbf; e = gid - 192; }
        else if (gid < 4480) { src = aw;  dst = awf; e = gid - 384; }
        else if (gid < 4544) { src = ab;  dst = abf; e = gid - 4480; }
        else if (gid < 5048) { src = kw_; dst = krw; e = gid - 4544; }
        else if (gid < 5552) { src = kh_; dst = krh; e = gid - 5048; }
        else if (gid < 5568) { zbuf[gid - 5552] = 0.f; return; }
        else return;
        dst[e] = fl ? bf2f(((const u16*)src)[e]) : ((const float*)src)[e];
    } else {                                 // xcvt: x -> bf16 (verified)
        const int g = (blk - 262) * 256 + threadIdx.x;     // 0..262143
        if (fl) {
            *(uint4*)(xbf + (size_t)g * 8) = *(const uint4*)(x0 + (size_t)g * 8);
        } else {
            const float* src = (const float*)x0 + (size_t)g * 8;
            float4 a = *(const float4*)src, b = *(const float4*)(src + 4);
            uint4 o;
            o.x = (u32)f2bf(a.x) | ((u32)f2bf(a.y) << 16);
            o.y = (u32)f2bf(a.z) | ((u32)f2bf(a.w) << 16);
            o.z = (u32)f2bf(b.x) | ((u32)f2bf(b.y) << 16);
            o.w = (u32)f2bf(b.z) | ((u32)f2bf(b.w) << 16);
            *(uint4*)(xbf + (size_t)g * 8) = o;
        }
    }
}

// ---------------------------------------------------------------------------
// qc: merged conv (blocks 0..511) + qkv (512..1023) — EXACT R12-verified
// configuration (145.3 us): coh-split conv, single M-tile per wave, rotating
// 2-slot row staging (35904 B -> 4 blocks/CU).
// ---------------------------------------------------------------------------
__global__ __launch_bounds__(256) void qc_kernel(
    const u16* __restrict__ xbf, const u16* __restrict__ wshC, const u16* __restrict__ wshQ,
    const float* __restrict__ cbf, const float* __restrict__ qbf_,
    const int* __restrict__ flagws,
    u16* __restrict__ kb16, float* __restrict__ qbuf, u16* __restrict__ vb16,
    void* __restrict__ out)
{
    __shared__ u16 xs[2 * 34 * 264];                        // 35904 B
    const int blk = blockIdx.x;
    const int t = threadIdx.x;
    const int lane = t & 63, wave = t >> 6;
    const int Mtile = wave & 1;
    const int l15 = lane & 15, quad = lane >> 4;

    if (blk < 512) {
        // ================= conv role (R12-verified) =================
        const int coh = blk & 1, row = blk >> 1;
        const int b = row >> 5, h = row & 31;
        const int fl = *flagws;
        const int tg0 = coh * 6 + (wave >> 1) * 3;
        f32x4 acc[3] = {{0,0,0,0},{0,0,0,0},{0,0,0,0}};

        #define STAGE_ROW(R, S)                                                  \
          do {                                                                   \
            const int hh = h + (R) - 1;                                          \
            if (t < 64) {                                                        \
                const int e = (t >> 5) ? 33 : 0, cq = t & 31;                    \
                *(uint4*)(xs + ((S) * 34 + e) * 264 + cq * 8) = make_uint4(0,0,0,0); \
            }                                                                    \
            const bool ok = (hh >= 0) && (hh < 32);                              \
            const u16* src = xbf + ((size_t)((b * 32 + (ok ? hh : 0)) * 32)) * 256; \
            _Pragma("unroll")                                                    \
            for (int i = 0; i < 4; ++i) {                                        \
                const int idx = t + i * 256;                                     \
                const int px = idx >> 5, cq = idx & 31;                          \
                uint4 v = ok ? *(const uint4*)(src + px * 256 + cq * 8)          \
                             : make_uint4(0, 0, 0, 0);                           \
                *(uint4*)(xs + ((S) * 34 + 1 + px) * 264 + cq * 8) = v;          \
            }                                                                    \
          } while (0)

        #define CONV_KH(KH, S)                                                   \
          do {                                                                   \
            _Pragma("unroll")                                                    \
            for (int kw = 0; kw < 3; ++kw) {                                     \
              const u16* ap = xs + ((S) * 34 + kw + Mtile * 16 + l15) * 264 + quad * 8; \
              _Pragma("unroll")                                                  \
              for (int ck = 0; ck < 8; ++ck) {                                   \
                const int kk = ((KH) * 3 + kw) * 8 + ck;                         \
                const bf16x8 av = *(const bf16x8*)(ap + ck * 32);                \
                const u16* wp = wshC + ((size_t)(kk * 12 + tg0) * 64 + lane) * 8;\
                const bf16x8 b0 = *(const bf16x8*)(wp);                          \
                const bf16x8 b1 = *(const bf16x8*)(wp + 512);                    \
                const bf16x8 b2 = *(const bf16x8*)(wp + 1024);                   \
                acc[0] = __builtin_amdgcn_mfma_f32_16x16x32_bf16(av, b0, acc[0], 0, 0, 0); \
                acc[1] = __builtin_amdgcn_mfma_f32_16x16x32_bf16(av, b1, acc[1], 0, 0, 0); \
                acc[2] = __builtin_amdgcn_mfma_f32_16x16x32_bf16(av, b2, acc[2], 0, 0, 0); \
              }                                                                  \
            }                                                                    \
          } while (0)

        STAGE_ROW(0, 0);
        STAGE_ROW(1, 1);
        __syncthreads();
        CONV_KH(0, 0);
        __syncthreads();                     // all waves done reading slot 0
        STAGE_ROW(2, 0);                     // overlaps with kh=1 compute below
        CONV_KH(1, 1);
        __syncthreads();                     // slot-0 writes visible
        CONV_KH(2, 0);

        const int px0 = Mtile * 16 + quad * 4;
        #pragma unroll
        for (int ti = 0; ti < 3; ++ti) {
            const int co = (tg0 + ti) * 16 + l15;
            const float bias = cbf[co];
            #pragma unroll
            for (int r = 0; r < 4; ++r) {
                const size_t oidx = ((size_t)row * 32 + px0 + r) * 256 + co;
                const float v = acc[ti][r] + bias;
                if (fl) ((u16*)out)[oidx] = f2bf(v);
                else    ((float*)out)[oidx] = v;
            }
        }
        #undef STAGE_ROW
        #undef CONV_KH
    } else {
        // ================= qkv role (R12-verified body) =================
        const int idx2 = blk - 512;
        const int coh = idx2 & 1, row = idx2 >> 1;
        const int b = row >> 5, h = row & 31;

        {
            const u16* src = xbf + (size_t)row * 8192;
            #pragma unroll
            for (int i = 0; i < 4; ++i) {
                const int idx = t + i * 256;
                const int px = idx >> 5, cq = idx & 31;
                *(uint4*)(xs + px * 264 + cq * 8) = *(const uint4*)(src + px * 256 + cq * 8);
            }
        }
        __syncthreads();

        const int tg0 = coh * 6 + (wave >> 1) * 3;
        f32x4 acc[3] = {{0,0,0,0},{0,0,0,0},{0,0,0,0}};

        const u16* ap = xs + (Mtile * 16 + l15) * 264 + quad * 8;
        #pragma unroll
        for (int kk = 0; kk < 8; ++kk) {
            const bf16x8 av = *(const bf16x8*)(ap + kk * 32);
            const u16* wp = wshQ + ((size_t)(kk * 12 + tg0) * 64 + lane) * 8;
            const bf16x8 b0 = *(const bf16x8*)(wp);
            const bf16x8 b1 = *(const bf16x8*)(wp + 512);
            const bf16x8 b2 = *(const bf16x8*)(wp + 1024);
            acc[0] = __builtin_amdgcn_mfma_f32_16x16x32_bf16(av, b0, acc[0], 0, 0, 0);
            acc[1] = __builtin_amdgcn_mfma_f32_16x16x32_bf16(av, b1, acc[1], 0, 0, 0);
            acc[2] = __builtin_amdgcn_mfma_f32_16x16x32_bf16(av, b2, acc[2], 0, 0, 0);
        }

        // D layout (verified): col = lane&15, row = quad*4 + reg
        const int px0 = Mtile * 16 + quad * 4;
        #pragma unroll
        for (int ti = 0; ti < 3; ++ti) {
            const int tg = tg0 + ti;
            const int o = tg * 16 + l15;
            const int third = tg >> 2;                      // 0=k,1=q,2=v (wave-uniform)
            const int within = o - third * 64;
            const int n = within >> 3, d = within & 7;
            const float bias = qbf_[o];
            #pragma unroll
            for (int r = 0; r < 4; ++r) {
                const int i = h * 32 + px0 + r;
                const size_t off = ((size_t)(b * 8 + n) * 1024 + i) * 8 + d;
                const float val = acc[ti][r] + bias;
                if (third == 0)      kb16[off] = f2bf(val);
                else if (third == 1) qbuf[off] = val * 0.51006973050f;  // 8^-.5 * log2e
                else                 vb16[off] = f2bf(val);
            }
        }
    }
}

// ---------------------------------------------------------------------------
// MFMA flash attention v10 + T5 setprio hints around the MFMA clusters
// (only change vs the R12-verified kernel; pure scheduler hint, no
// correctness impact). Waves are pair-independent until the final barrier,
// so prio(1) lets MFMA-entering waves preempt exp/load-issuing waves.
// ---------------------------------------------------------------------------
#define ATTN_STEPA(C, KA, KB, OACC)                                            \
  do {                                                                         \
    const int c_ = (C);                                                        \
    const float rhv = sRH[c_ * 36 + pair * 16 + l15];                          \
    f32x4 acc0, acc1;                                                          \
    acc0[0] = rhv + rw0[0]; acc0[1] = rhv + rw0[1];                            \
    acc0[2] = rhv + rw0[2]; acc0[3] = rhv + rw0[3];                            \
    acc1[0] = rhv + rw1[0]; acc1[1] = rhv + rw1[1];                            \
    acc1[2] = rhv + rw1[2]; acc1[3] = rhv + rw1[3];                            \
    __builtin_amdgcn_s_setprio(1);                                             \
    acc0 = __builtin_amdgcn_mfma_f32_16x16x32_bf16(KA, Aq.v, acc0, 0, 0, 0);   \
    acc1 = __builtin_amdgcn_mfma_f32_16x16x32_bf16(KB, Aq.v, acc1, 0, 0, 0);   \
    __builtin_amdgcn_s_setprio(0);                                             \
    if (c_ + 4 < 32) {            /* prefetch 4 chunks ahead (ping-pong) */    \
      KA = *(const bf16x8*)(kp0 + (c_ + 4) * 256);                             \
      KB = *(const bf16x8*)(kp1 + (c_ + 4) * 256);                             \
    }                                                                          \
    union { u16 a[8]; bf16x8 v; } pf;                                          \
    pf.a[0] = bf16u(fexp2(fminf(acc0[0], 80.0f)));                             \
    pf.a[1] = bf16u(fexp2(fminf(acc0[1], 80.0f)));                             \
    pf.a[2] = bf16u(fexp2(fminf(acc0[2], 80.0f)));                             \
    pf.a[3] = bf16u(fexp2(fminf(acc0[3], 80.0f)));                             \
    pf.a[4] = bf16u(fexp2(fminf(acc1[0], 80.0f)));                             \
    pf.a[5] = bf16u(fexp2(fminf(acc1[1], 80.0f)));                             \
    pf.a[6] = bf16u(fexp2(fminf(acc1[2], 80.0f)));                             \
    pf.a[7] = bf16u(fexp2(fminf(acc1[3], 80.0f)));                             \
    bf16x8 Av;                                                                 \
    if (l15 < 8) Av = *(const bf16x8*)(sVT + l15 * 1032 + c_ * 32 + quad * 8); \
    else         Av = ONE.v;                                                   \
    __builtin_amdgcn_s_setprio(1);                                             \
    OACC = __builtin_amdgcn_mfma_f32_16x16x32_bf16(Av, pf.v, OACC, 0, 0, 0);   \
    __builtin_amdgcn_s_setprio(0);                                             \
  } while (0)

__global__ __launch_bounds__(256) void attn_mfma_kernel(
    const u16* __restrict__ kb16, const float* __restrict__ qbuf, const u16* __restrict__ vb16,
    const float* __restrict__ krw, const float* __restrict__ krh,
    float* __restrict__ attnbuf)
{
    const int qb = blockIdx.x;           // 0..31 (32 q-rows each)
    const int bn = blockIdx.y;           // 0..63
    const int b = bn >> 3, hn = bn & 7;
    const int t = threadIdx.x;
    const int i0 = qb * 32;

    __shared__ __align__(16) u16   sVT[8 * 1032];   // [d][key] bf16 (pad)  16512 B
    __shared__ __align__(16) u16   sRW[32 * 40];    // [ilocal][wk] bf16     2560 B
    __shared__ __align__(16) float sRH[32 * 36];    // [hk][ilocal] f32      4608 B
    __shared__ __align__(16) float sRed[2 * 64 * 4];// pair partials         2048 B

    // ---- stage V^T from bf16 vbuf (no conversion) — verified ----
    const u16* vg = vb16 + (size_t)bn * 8192;
    #pragma unroll
    for (int k4 = 0; k4 < 4; k4++) {
        const int key = t + k4 * 256;                 // 0..1023
        uint4 vv = *(const uint4*)(vg + key * 8);
        sVT[0 * 1032 + key] = (u16)(vv.x);  sVT[1 * 1032 + key] = (u16)(vv.x >> 16);
        sVT[2 * 1032 + key] = (u16)(vv.y);  sVT[3 * 1032 + key] = (u16)(vv.y >> 16);
        sVT[4 * 1032 + key] = (u16)(vv.z);  sVT[5 * 1032 + key] = (u16)(vv.z >> 16);
        sVT[6 * 1032 + key] = (u16)(vv.w);  sVT[7 * 1032 + key] = (u16)(vv.w >> 16);
    }
    // ---- rel tables (verified math; 32 q-rows) ----
    #pragma unroll
    for (int k8 = 0; k8 < 4; k8++) {
        const int idx = t + k8 * 256;                 // 0..1023
        const int il = idx >> 5, w = idx & 31;        // il 0..31
        const int i = i0 + il;
        const float* q = qbuf + ((size_t)bn * 1024 + i) * 8;
        float4 qa = *(const float4*)q, qc = *(const float4*)(q + 4);
        const float* rp = krw + (size_t)(w - (i & 31) + 31) * 8;
        float4 ra = *(const float4*)rp, rc = *(const float4*)(rp + 4);
        sRW[il * 40 + w] = f2bf(qa.x*ra.x + qa.y*ra.y + qa.z*ra.z + qa.w*ra.w
                              + qc.x*rc.x + qc.y*rc.y + qc.z*rc.z + qc.w*rc.w);
        const float* hp = krh + (size_t)(w - (i >> 5) + 31) * 8;
        float4 ha = *(const float4*)hp, hc = *(const float4*)(hp + 4);
        sRH[w * 36 + il] = qa.x*ha.x + qa.y*ha.y + qa.z*ha.z + qa.w*ha.w
                         + qc.x*hc.x + qc.y*hc.y + qc.z*hc.z + qc.w*hc.w;
    }
    __syncthreads();

    const int lane = t & 63, wave = t >> 6;
    const int pair = wave >> 1, sub = wave & 1;
    const int l15 = lane & 15, quad = lane >> 4;

    union Frag { u16 a[8]; bf16x8 v; };
    Frag Aq;                                   // Q fragment (B operand)
    {
        const float* q = qbuf + ((size_t)bn * 1024 + i0 + pair * 16 + l15) * 8;
        float4 qa = *(const float4*)q, qc = *(const float4*)(q + 4);
        Aq.a[0] = f2bf(qa.x); Aq.a[1] = f2bf(qa.y); Aq.a[2] = f2bf(qa.z); Aq.a[3] = f2bf(qa.w);
        Aq.a[4] = f2bf(qc.x); Aq.a[5] = f2bf(qc.y); Aq.a[6] = f2bf(qc.z); Aq.a[7] = f2bf(qc.w);
        if (quad != 0) {
            #pragma unroll
            for (int j = 0; j < 8; j++) Aq.a[j] = 0;
        }
    }
    const bf16x8 Arw = *(const bf16x8*)(sRW + (pair * 16 + l15) * 40 + quad * 8);

    // Selector fragments (verified): S0 -> k=pi0(l15), S1 -> k=pi1(l15).
    Frag S0, S1, ONE;
    #pragma unroll
    for (int j = 0; j < 8; j++) { S0.a[j] = 0; S1.a[j] = 0; ONE.a[j] = 0x3F80; }
    if (quad == (l15 >> 2)) {
        S0.a[l15 & 3]       = 0x3F80;
        S1.a[4 + (l15 & 3)] = 0x3F80;
    }

    // Hoisted rel-W results (chunk-invariant).
    f32x4 zero4 = {0.f, 0.f, 0.f, 0.f};
    const f32x4 rw0 = __builtin_amdgcn_mfma_f32_16x16x32_bf16(S0.v, Arw, zero4, 0, 0, 0);
    const f32x4 rw1 = __builtin_amdgcn_mfma_f32_16x16x32_bf16(S1.v, Arw, zero4, 0, 0, 0);

    // K row pointers — uniform across quads (verified).
    const u16* kg = kb16 + (size_t)bn * 8192;
    const int s = l15 >> 2, rr = l15 & 3;
    const u16* kp0 = kg + (size_t)(8 * s + rr) * 8;          // pi0 rows
    const u16* kp1 = kg + (size_t)(8 * s + 4 + rr) * 8;      // pi1 rows

    f32x4 oaccE = {0.f, 0.f, 0.f, 0.f};
    f32x4 oaccO = {0.f, 0.f, 0.f, 0.f};

    // This wave's chunks: sub, sub+2, ..., sub+30 (16 chunks).
    bf16x8 kAa = *(const bf16x8*)(kp0 + sub * 256);
    bf16x8 kBa = *(const bf16x8*)(kp1 + sub * 256);
    bf16x8 kAb = *(const bf16x8*)(kp0 + (sub + 2) * 256);
    bf16x8 kBb = *(const bf16x8*)(kp1 + (sub + 2) * 256);

    for (int c2 = sub; c2 < 32; c2 += 4) {
        ATTN_STEPA(c2,     kAa, kBa, oaccE);
        ATTN_STEPA(c2 + 2, kAb, kBb, oaccO);
    }

    f32x4 oacc;
    oacc[0] = oaccE[0] + oaccO[0];
    oacc[1] = oaccE[1] + oaccO[1];
    oacc[2] = oaccE[2] + oaccO[2];
    oacc[3] = oaccE[3] + oaccO[3];

    // Pair reduction: sub==1 writes partials; sub==0 adds.
    if (sub == 1) *(f32x4*)(sRed + (pair * 64 + lane) * 4) = oacc;
    __syncthreads();
    if (sub == 0) {
        const f32x4 part = *(const f32x4*)(sRed + (pair * 64 + lane) * 4);
        oacc[0] += part[0]; oacc[1] += part[1];
        oacc[2] += part[2]; oacc[3] += part[3];

        // D2[row][q=l15]: rows 0-7 = O^T[d][q] (quads 0,1), rows 8-15 = l[q].
        const float lr = __shfl(oacc[0], 32 + l15, 64);   // (l15, quad=2) row 8
        const float inv = 1.0f / fmaxf(lr, 1e-30f);
        if (quad < 2) {
            float4 o;
            o.x = oacc[0] * inv; o.y = oacc[1] * inv;
            o.z = oacc[2] * inv; o.w = oacc[3] * inv;
            *(float4*)(attnbuf + ((size_t)b * 1024 + i0 + pair * 16 + l15) * 64
                       + hn * 8 + quad * 4) = o;
        }
    }
}

// ---------------------------------------------------------------------------
// Output projection (verified body; flag read from ws).
// ---------------------------------------------------------------------------
__global__ __launch_bounds__(256) void proj_kernel(
    const float* __restrict__ attnbuf, const float* __restrict__ awf, const float* __restrict__ abf,
    const int* __restrict__ flagws, void* __restrict__ out)
{
    const int g = blockIdx.x * 256 + threadIdx.x;
    const int px = g >> 6, o = g & 63;
    const float* ar = attnbuf + (size_t)px * 64;
    float acc = abf[o];
    #pragma unroll 8
    for (int c = 0; c < 64; c++) acc += ar[c] * awf[c * 64 + o];
    if (*flagws) ((u16*)out)[(size_t)px * 256 + 192 + o] = f2bf(acc);
    else         ((float*)out)[(size_t)px * 256 + 192 + o] = acc;
}

// ---------------------------------------------------------------------------
extern "C" void kernel_launch(void* const* d_in, const int* in_sizes, int n_in,
                              void* d_out, int out_size, void* d_ws, size_t ws_size,
                              hipStream_t stream)
{
    float* ws = (float*)d_ws;
    int*   flag = (int*)(ws + FLAG_OFF);
    float* zbuf = ws + ZERO_OFF;
    u16*   wsh  = (u16*)(ws + WSH_OFF);
    float* awf  = ws + AWF_OFF;
    float* cbf  = ws + CBF_OFF;
    float* qbf  = ws + QBF_OFF;
    float* abf  = ws + ABF_OFF;
    float* krw  = ws + KRW_OFF;
    float* krh  = ws + KRH_OFF;
    u16*   kb16 = (u16*)(ws + KB_OFF);
    float* qbuf = ws + QB_OFF;
    u16*   vb16 = (u16*)(ws + VB_OFF);
    float* atb  = ws + AT_OFF;
    u16*   xbf  = (u16*)(ws + XBF_OFF);
    u16*   wshQ = (u16*)(ws + WSHQ_OFF);

    prepx_kernel<<<1286, 256, 0, stream>>>(
        (const u16*)d_in[0],
        d_in[1], d_in[3], d_in[2], d_in[4], d_in[5], d_in[6], d_in[7], d_in[8],
        wsh, wshQ, cbf, qbf, awf, abf, krw, krh, zbuf, flag, xbf);

    qc_kernel<<<1024, 256, 0, stream>>>(
        xbf, wsh, wshQ, cbf, qbf, flag, kb16, qbuf, vb16, d_out);

    attn_mfma_kernel<<<dim3(32, 64), 256, 0, stream>>>(kb16, qbuf, vb16, krw, krh, atb);
    proj_kernel     <<<2048,         256, 0, stream>>>(atb, awf, abf, flag, d_out);
}